// Round 4
// baseline (432.465 us; speedup 1.0000x reference)
//
#include <hip/hip_runtime.h>
#include <stdint.h>

#define DIMSZ 2048
#define NH 16
#define NKV 4
#define HD 128
#define BATCH 2
#define SEQ 2048
#define MROWS (BATCH*SEQ)          // 4096
#define NQKV (NH*HD + 2*NKV*HD)    // 3072

typedef unsigned short u16;
typedef float f32x4 __attribute__((ext_vector_type(4)));
typedef short short8 __attribute__((ext_vector_type(8)));
typedef __bf16 bf16x8 __attribute__((ext_vector_type(8)));
typedef unsigned short u16x4 __attribute__((ext_vector_type(4)));

__device__ __forceinline__ u16 f2bf(float f) {
  __bf16 h = (__bf16)f;           // native RNE convert (v_cvt_pk_bf16_f32)
  return __builtin_bit_cast(u16, h);
}

__device__ __forceinline__ float bf2f(u16 h) {
  union { uint32_t u; float f; } v; v.u = ((uint32_t)h) << 16; return v.f;
}

__device__ __forceinline__ void async16(void* lds, const void* g) {
  __builtin_amdgcn_global_load_lds(
      (const __attribute__((address_space(1))) void*)(g),
      (__attribute__((address_space(3))) void*)(lds), 16, 0, 0);
}

__device__ __forceinline__ bf16x8 load_frag(const u16* p) {
  short8 v = *reinterpret_cast<const short8*>(p);
  return __builtin_bit_cast(bf16x8, v);
}

// ---------------- cast x fp32 -> bf16 ----------------
__global__ void cast_x_kernel(const float* __restrict__ x, u16* __restrict__ xb) {
  int i = (blockIdx.x * blockDim.x + threadIdx.x) * 4;
  float4 v = *reinterpret_cast<const float4*>(x + i);
  u16x4 o;
  o.x = f2bf(v.x); o.y = f2bf(v.y); o.z = f2bf(v.z); o.w = f2bf(v.w);
  *reinterpret_cast<u16x4*>(xb + i) = o;
}

// ------------- transpose-cast weight: src[K][N] f32 -> dst[N][K] bf16 -------------
__global__ __launch_bounds__(1024) void wtrans_kernel(const float* __restrict__ src,
                                                      u16* __restrict__ dst, int K, int N) {
  __shared__ float t[32][33];
  int k0 = blockIdx.x * 32, n0 = blockIdx.y * 32;
  int tx = threadIdx.x, ty = threadIdx.y;
  t[ty][tx] = src[(size_t)(k0 + ty) * N + n0 + tx];
  __syncthreads();
  dst[(size_t)(n0 + ty) * K + k0 + tx] = f2bf(t[tx][ty]);
}

// ---------------- GEMM: C[M][N] = A[M][K] bf16 @ BT[N][K] bf16 ----------------
template <bool BF16OUT>
__global__ __launch_bounds__(256) void gemm_bt_kernel(const u16* __restrict__ A,
                                                      const u16* __restrict__ BT,
                                                      void* __restrict__ Cp,
                                                      int M, int N, int K) {
  __shared__ u16 As[128 * 32];
  __shared__ u16 Bs[128 * 32];
  const int tid = threadIdx.x;
  const int wave = tid >> 6, lane = tid & 63;
  const int l16 = lane & 15, lg = lane >> 4;
  const int bm = blockIdx.y * 128, bn = blockIdx.x * 128;
  const int wrow = (wave >> 1) * 64, wcol = (wave & 1) * 64;
  const int lrow = lane >> 2;          // 0..15 within 16-row chunk
  const int lcol = (lane & 3) * 8;     // 0,8,16,24
  f32x4 acc[4][4] = {};
  for (int k0 = 0; k0 < K; k0 += 32) {
    __syncthreads();
#pragma unroll
    for (int i = 0; i < 2; ++i) {
      int chunk = i * 4 + wave;        // 0..7
      int row = chunk * 16 + lrow;
      async16(&As[chunk * 512], &A[(size_t)(bm + row) * K + k0 + lcol]);
      async16(&Bs[chunk * 512], &BT[(size_t)(bn + row) * K + k0 + lcol]);
    }
    __syncthreads();
    bf16x8 af[4], bfr[4];
#pragma unroll
    for (int mb = 0; mb < 4; ++mb) af[mb] = load_frag(&As[(wrow + mb * 16 + l16) * 32 + lg * 8]);
#pragma unroll
    for (int nb = 0; nb < 4; ++nb) bfr[nb] = load_frag(&Bs[(wcol + nb * 16 + l16) * 32 + lg * 8]);
#pragma unroll
    for (int mb = 0; mb < 4; ++mb)
#pragma unroll
      for (int nb = 0; nb < 4; ++nb)
        acc[mb][nb] = __builtin_amdgcn_mfma_f32_16x16x32_bf16(af[mb], bfr[nb], acc[mb][nb], 0, 0, 0);
  }
#pragma unroll
  for (int mb = 0; mb < 4; ++mb)
#pragma unroll
    for (int nb = 0; nb < 4; ++nb)
#pragma unroll
      for (int r = 0; r < 4; ++r) {
        size_t idx = (size_t)(bm + wrow + mb * 16 + lg * 4 + r) * N + bn + wcol + nb * 16 + l16;
        if (BF16OUT) ((u16*)Cp)[idx] = f2bf(acc[mb][nb][r]);
        else         ((float*)Cp)[idx] = acc[mb][nb][r];
      }
}

// ---------------- RoPE + pack Q and K (bf16 in / bf16 out) ----------------
// grid (1024, 20): y = head index (0..15 -> Q, 16..19 -> K)
__global__ void rope_qk_kernel(const u16* __restrict__ qkv, const float* __restrict__ fc,
                               const float* __restrict__ fs, u16* __restrict__ Qb,
                               u16* __restrict__ Kb) {
  int gi = blockIdx.x * blockDim.x + threadIdx.x; // (b*SEQ+s)*64 + i
  int i = gi & 63;
  int t = gi >> 6;          // b*SEQ + s
  int s = t & (SEQ - 1), b = t >> 11;
  int hh = blockIdx.y;
  float c = fc[s * 64 + i], sn = fs[s * 64 + i];
  if (hh < 16) {
    uint32_t pr = *reinterpret_cast<const uint32_t*>(&qkv[(size_t)t * NQKV + hh * HD + 2 * i]);
    float tr = bf2f((u16)(pr & 0xffff)), ti = bf2f((u16)(pr >> 16));
    const float qs = 0.12751689760098266f; // log2(e)/sqrt(128)
    uint32_t w = (uint32_t)f2bf((tr * c - ti * sn) * qs) |
                 ((uint32_t)f2bf((tr * sn + ti * c) * qs) << 16);
    *reinterpret_cast<uint32_t*>(&Qb[((size_t)(b * NH + hh) * SEQ + s) * HD + 2 * i]) = w;
  } else {
    int kh = hh - 16;
    uint32_t pr = *reinterpret_cast<const uint32_t*>(&qkv[(size_t)t * NQKV + NH * HD + kh * HD + 2 * i]);
    float tr = bf2f((u16)(pr & 0xffff)), ti = bf2f((u16)(pr >> 16));
    uint32_t w = (uint32_t)f2bf(tr * c - ti * sn) |
                 ((uint32_t)f2bf(tr * sn + ti * c) << 16);
    *reinterpret_cast<uint32_t*>(&Kb[((size_t)(b * NKV + kh) * SEQ + s) * HD + 2 * i]) = w;
  }
}

// ---------------- V transpose: qkv v-part [s][d] bf16 -> VT [d][s] bf16 ----------------
__global__ __launch_bounds__(1024) void vtrans_kernel(const u16* __restrict__ qkv,
                                                      u16* __restrict__ vt) {
  __shared__ u16 t[32][33];
  int s0 = blockIdx.x * 32, d0 = blockIdx.y * 32;
  int bk = blockIdx.z;
  int b = bk >> 2, kh = bk & 3;
  int tx = threadIdx.x, ty = threadIdx.y;
  t[ty][tx] = qkv[(size_t)(b * SEQ + s0 + ty) * NQKV + NH * HD + NKV * HD + kh * HD + d0 + tx];
  __syncthreads();
  vt[((size_t)(b * NKV + kh) * HD + d0 + ty) * SEQ + s0 + tx] = t[tx][ty];
}

// ---------------- causal flash attention, L2-direct K/V ----------------
// grid (1024), 256 threads. bid&7 -> XCD -> (b,kvh): each XCD's L2 caches
// exactly its own 1MB of K+V. No LDS staging, no barriers: each wave owns 16
// q-rows, reads K/V fragments straight from L2. Per-CU causal balance: the
// 4 blocks/CU pair qblk t with 31-t (66 steps each CU).
__global__ __launch_bounds__(256, 4) void attn_kernel(const u16* __restrict__ Q,
                                                      const u16* __restrict__ Kc,
                                                      const u16* __restrict__ VT,
                                                      u16* __restrict__ AO) {
  __shared__ u16 Ps[4][16 * 64];    // per-wave P tile [qrow][key], swizzled
  const int bid = blockIdx.x;
  const int xcd = bid & 7, j = bid >> 3;      // j 0..127
  const int b = xcd >> 2, kvh = xcd & 3;
  const int hq = j >> 5, t = j & 31;
  const int qblk = (hq & 2) ? t : (31 - t);
  const int h = kvh * 4 + hq;
  const int tid = threadIdx.x, wave = tid >> 6, lane = tid & 63;
  const int l16 = lane & 15, lg = lane >> 4;
  const int qrow0 = qblk * 64 + wave * 16;

  const u16* Kb = Kc + (size_t)(b * NKV + kvh) * SEQ * HD;
  const u16* Vb = VT + (size_t)(b * NKV + kvh) * HD * SEQ;

  bf16x8 qf[4];
  const u16* Qbase = Q + ((size_t)(b * NH + h) * SEQ + qrow0 + l16) * HD;
#pragma unroll
  for (int c = 0; c < 4; ++c) qf[c] = load_frag(Qbase + c * 32 + lg * 8);

  f32x4 o[8] = {};
  float m[4], l[4];
#pragma unroll
  for (int r = 0; r < 4; ++r) { m[r] = -3e38f; l[r] = 0.f; }

  for (int kt = 0; kt <= qblk; ++kt) {
    const int k0 = kt * 64;

    f32x4 s[4] = {};
    __builtin_amdgcn_s_setprio(1);
#pragma unroll
    for (int cb = 0; cb < 4; ++cb) {
#pragma unroll
      for (int c = 0; c < 4; ++c) {
        bf16x8 kf = load_frag(&Kb[(size_t)(k0 + cb * 16 + l16) * HD + c * 32 + lg * 8]);
        s[cb] = __builtin_amdgcn_mfma_f32_16x16x32_bf16(qf[c], kf, s[cb], 0, 0, 0);
      }
    }
    __builtin_amdgcn_s_setprio(0);

    if (kt == qblk) { // only the diagonal tile needs masking
#pragma unroll
      for (int cb = 0; cb < 4; ++cb) {
        int key = k0 + cb * 16 + l16;
#pragma unroll
        for (int r = 0; r < 4; ++r) {
          int rq = qrow0 + lg * 4 + r;
          if (key > rq) s[cb][r] = -1e30f;
        }
      }
    }

    // tile max per row
    float v0[4];
#pragma unroll
    for (int r = 0; r < 4; ++r) {
      float v = fmaxf(fmaxf(s[0][r], s[1][r]), fmaxf(s[2][r], s[3][r]));
      v = fmaxf(v, __shfl_xor(v, 1));
      v = fmaxf(v, __shfl_xor(v, 2));
      v = fmaxf(v, __shfl_xor(v, 4));
      v = fmaxf(v, __shfl_xor(v, 8));
      v0[r] = v;
    }
    // defer-max: only rescale when some row grew by > 8 (exp2 domain)
    bool need = (v0[0] > m[0] + 8.f) || (v0[1] > m[1] + 8.f) ||
                (v0[2] > m[2] + 8.f) || (v0[3] > m[3] + 8.f);
    if (__any(need)) {
#pragma unroll
      for (int r = 0; r < 4; ++r) {
        float newm = fmaxf(m[r], v0[r]);
        float sc = exp2f(m[r] - newm);
        l[r] *= sc; m[r] = newm;
#pragma unroll
        for (int db = 0; db < 8; ++db) o[db][r] *= sc;
      }
    }
#pragma unroll
    for (int r = 0; r < 4; ++r) {
      float sum = 0.f;
      int prow = lg * 4 + r;
#pragma unroll
      for (int cb = 0; cb < 4; ++cb) {
        float p = exp2f(s[cb][r] - m[r]);
        sum += p;
        Ps[wave][(prow * 64 + cb * 16 + l16) ^ ((prow & 7) << 3)] = f2bf(p);
      }
      sum += __shfl_xor(sum, 1);
      sum += __shfl_xor(sum, 2);
      sum += __shfl_xor(sum, 4);
      sum += __shfl_xor(sum, 8);
      l[r] += sum;
    }

    bf16x8 pf[2];
#pragma unroll
    for (int c = 0; c < 2; ++c)
      pf[c] = load_frag(&Ps[wave][(l16 * 64 + c * 32 + lg * 8) ^ ((l16 & 7) << 3)]);
    __builtin_amdgcn_s_setprio(1);
#pragma unroll
    for (int db = 0; db < 8; ++db) {
#pragma unroll
      for (int c = 0; c < 2; ++c) {
        bf16x8 vf = load_frag(&Vb[(size_t)(db * 16 + l16) * SEQ + k0 + c * 32 + lg * 8]);
        o[db] = __builtin_amdgcn_mfma_f32_16x16x32_bf16(pf[c], vf, o[db], 0, 0, 0);
      }
    }
    __builtin_amdgcn_s_setprio(0);
  }

#pragma unroll
  for (int r = 0; r < 4; ++r) {
    float inv = 1.f / l[r];
    int rq = qrow0 + lg * 4 + r;
    size_t dst = ((size_t)(b * SEQ + rq) * NH + h) * HD;
#pragma unroll
    for (int db = 0; db < 8; ++db)
      AO[dst + db * 16 + l16] = f2bf(o[db][r] * inv);
  }
}

extern "C" void kernel_launch(void* const* d_in, const int* in_sizes, int n_in,
                              void* d_out, int out_size, void* d_ws, size_t ws_size,
                              hipStream_t stream) {
  (void)in_sizes; (void)n_in; (void)out_size; (void)ws_size;
  const float* x  = (const float*)d_in[0];
  const float* fc = (const float*)d_in[1];
  const float* fs = (const float*)d_in[2];
  const float* wq = (const float*)d_in[3];
  const float* wk = (const float*)d_in[4];
  const float* wv = (const float*)d_in[5];
  const float* wo = (const float*)d_in[6];
  float* out = (float*)d_out;

  char* ws = (char*)d_ws;
  // layout (bytes):
  u16*  xb    = (u16*)(ws);                      // 4096*2048*2    = 16,777,216
  u16*  wtqkv = (u16*)(ws + 16777216);           // 3072*2048*2    = 12,582,912
  u16*  wto   = (u16*)(ws + 29360128);           // 2048*2048*2    =  8,388,608
  u16*  qkv   = (u16*)(ws + 37748736);           // 4096*3072*2    = 25,165,824 (bf16)
  u16*  Qb    = (u16*)(ws + 62914560);           // 2*16*2048*128*2= 16,777,216
  u16*  Kb    = (u16*)(ws + 79691776);           // 2*4*2048*128*2 =  4,194,304
  u16*  VTb   = (u16*)(ws + 83886080);           // 2*4*128*2048*2 =  4,194,304
  u16*  AOb   = (u16*)(ws + 37748736);           // aliases qkv (dead after pack)

  dim3 tb(32, 32);
  cast_x_kernel<<<dim3(8192), dim3(256), 0, stream>>>(x, xb);
  wtrans_kernel<<<dim3(64, 64), tb, 0, stream>>>(wq, wtqkv, 2048, 2048);
  wtrans_kernel<<<dim3(64, 16), tb, 0, stream>>>(wk, wtqkv + (size_t)2048 * 2048, 2048, 512);
  wtrans_kernel<<<dim3(64, 16), tb, 0, stream>>>(wv, wtqkv + (size_t)2560 * 2048, 2048, 512);
  wtrans_kernel<<<dim3(64, 64), tb, 0, stream>>>(wo, wto, 2048, 2048);

  gemm_bt_kernel<true><<<dim3(24, 32), dim3(256), 0, stream>>>(xb, wtqkv, qkv, MROWS, NQKV, DIMSZ);

  rope_qk_kernel<<<dim3(1024, 20), dim3(256), 0, stream>>>(qkv, fc, fs, Qb, Kb);
  vtrans_kernel<<<dim3(64, 4, 8), tb, 0, stream>>>(qkv, VTb);

  attn_kernel<<<dim3(1024), dim3(256), 0, stream>>>(Qb, Kb, VTb, AOb);

  gemm_bt_kernel<false><<<dim3(16, 32), dim3(256), 0, stream>>>(AOb, wto, out, MROWS, DIMSZ, DIMSZ);
}

// Round 5
// 289.249 us; speedup vs baseline: 1.4951x; 1.4951x over previous
//
#include <hip/hip_runtime.h>
#include <stdint.h>

#define DIMSZ 2048
#define NH 16
#define NKV 4
#define HD 128
#define BATCH 2
#define SEQ 2048
#define MROWS (BATCH*SEQ)          // 4096
#define NQKV (NH*HD + 2*NKV*HD)    // 3072

typedef unsigned short u16;
typedef float f32x4 __attribute__((ext_vector_type(4)));
typedef short short8 __attribute__((ext_vector_type(8)));
typedef __bf16 bf16x8 __attribute__((ext_vector_type(8)));
typedef unsigned short u16x4 __attribute__((ext_vector_type(4)));

__device__ __forceinline__ u16 f2bf(float f) {
  __bf16 h = (__bf16)f;           // native RNE convert
  return __builtin_bit_cast(u16, h);
}

__device__ __forceinline__ float bf2f(u16 h) {
  union { uint32_t u; float f; } v; v.u = ((uint32_t)h) << 16; return v.f;
}

__device__ __forceinline__ void async16(void* lds, const void* g) {
  __builtin_amdgcn_global_load_lds(
      (const __attribute__((address_space(1))) void*)(g),
      (__attribute__((address_space(3))) void*)(lds), 16, 0, 0);
}

__device__ __forceinline__ bf16x8 load_frag(const u16* p) {
  short8 v = *reinterpret_cast<const short8*>(p);
  return __builtin_bit_cast(bf16x8, v);
}

// ---------------- cast x fp32 -> bf16 ----------------
__global__ void cast_x_kernel(const float* __restrict__ x, u16* __restrict__ xb) {
  int i = (blockIdx.x * blockDim.x + threadIdx.x) * 4;
  float4 v = *reinterpret_cast<const float4*>(x + i);
  u16x4 o;
  o.x = f2bf(v.x); o.y = f2bf(v.y); o.z = f2bf(v.z); o.w = f2bf(v.w);
  *reinterpret_cast<u16x4*>(xb + i) = o;
}

// ------------- transpose-cast weight: src[K][N] f32 -> dst[N][K] bf16 -------------
__global__ __launch_bounds__(1024) void wtrans_kernel(const float* __restrict__ src,
                                                      u16* __restrict__ dst, int K, int N) {
  __shared__ float t[32][33];
  int k0 = blockIdx.x * 32, n0 = blockIdx.y * 32;
  int tx = threadIdx.x, ty = threadIdx.y;
  t[ty][tx] = src[(size_t)(k0 + ty) * N + n0 + tx];
  __syncthreads();
  dst[(size_t)(n0 + ty) * K + k0 + tx] = f2bf(t[tx][ty]);
}

// ---------------- GEMM: C[M][N] = A[M][K] bf16 @ BT[N][K] bf16 ----------------
template <bool BF16OUT>
__global__ __launch_bounds__(256) void gemm_bt_kernel(const u16* __restrict__ A,
                                                      const u16* __restrict__ BT,
                                                      void* __restrict__ Cp,
                                                      int M, int N, int K) {
  __shared__ u16 As[128 * 32];
  __shared__ u16 Bs[128 * 32];
  const int tid = threadIdx.x;
  const int wave = tid >> 6, lane = tid & 63;
  const int l16 = lane & 15, lg = lane >> 4;
  const int bm = blockIdx.y * 128, bn = blockIdx.x * 128;
  const int wrow = (wave >> 1) * 64, wcol = (wave & 1) * 64;
  const int lrow = lane >> 2;          // 0..15 within 16-row chunk
  const int lcol = (lane & 3) * 8;     // 0,8,16,24
  f32x4 acc[4][4] = {};
  for (int k0 = 0; k0 < K; k0 += 32) {
    __syncthreads();
#pragma unroll
    for (int i = 0; i < 2; ++i) {
      int chunk = i * 4 + wave;        // 0..7
      int row = chunk * 16 + lrow;
      async16(&As[chunk * 512], &A[(size_t)(bm + row) * K + k0 + lcol]);
      async16(&Bs[chunk * 512], &BT[(size_t)(bn + row) * K + k0 + lcol]);
    }
    __syncthreads();
    bf16x8 af[4], bfr[4];
#pragma unroll
    for (int mb = 0; mb < 4; ++mb) af[mb] = load_frag(&As[(wrow + mb * 16 + l16) * 32 + lg * 8]);
#pragma unroll
    for (int nb = 0; nb < 4; ++nb) bfr[nb] = load_frag(&Bs[(wcol + nb * 16 + l16) * 32 + lg * 8]);
#pragma unroll
    for (int mb = 0; mb < 4; ++mb)
#pragma unroll
      for (int nb = 0; nb < 4; ++nb)
        acc[mb][nb] = __builtin_amdgcn_mfma_f32_16x16x32_bf16(af[mb], bfr[nb], acc[mb][nb], 0, 0, 0);
  }
#pragma unroll
  for (int mb = 0; mb < 4; ++mb)
#pragma unroll
    for (int nb = 0; nb < 4; ++nb)
#pragma unroll
      for (int r = 0; r < 4; ++r) {
        size_t idx = (size_t)(bm + wrow + mb * 16 + lg * 4 + r) * N + bn + wcol + nb * 16 + l16;
        if (BF16OUT) ((u16*)Cp)[idx] = f2bf(acc[mb][nb][r]);
        else         ((float*)Cp)[idx] = acc[mb][nb][r];
      }
}

// ---------------- RoPE + pack Q and K (bf16 in / bf16 out) ----------------
// grid (1024, 20): y = head index (0..15 -> Q, 16..19 -> K)
__global__ void rope_qk_kernel(const u16* __restrict__ qkv, const float* __restrict__ fc,
                               const float* __restrict__ fs, u16* __restrict__ Qb,
                               u16* __restrict__ Kb) {
  int gi = blockIdx.x * blockDim.x + threadIdx.x; // (b*SEQ+s)*64 + i
  int i = gi & 63;
  int t = gi >> 6;          // b*SEQ + s
  int s = t & (SEQ - 1), b = t >> 11;
  int hh = blockIdx.y;
  float c = fc[s * 64 + i], sn = fs[s * 64 + i];
  if (hh < 16) {
    uint32_t pr = *reinterpret_cast<const uint32_t*>(&qkv[(size_t)t * NQKV + hh * HD + 2 * i]);
    float tr = bf2f((u16)(pr & 0xffff)), ti = bf2f((u16)(pr >> 16));
    const float qs = 0.12751689760098266f; // log2(e)/sqrt(128)
    uint32_t w = (uint32_t)f2bf((tr * c - ti * sn) * qs) |
                 ((uint32_t)f2bf((tr * sn + ti * c) * qs) << 16);
    *reinterpret_cast<uint32_t*>(&Qb[((size_t)(b * NH + hh) * SEQ + s) * HD + 2 * i]) = w;
  } else {
    int kh = hh - 16;
    uint32_t pr = *reinterpret_cast<const uint32_t*>(&qkv[(size_t)t * NQKV + NH * HD + kh * HD + 2 * i]);
    float tr = bf2f((u16)(pr & 0xffff)), ti = bf2f((u16)(pr >> 16));
    uint32_t w = (uint32_t)f2bf(tr * c - ti * sn) |
                 ((uint32_t)f2bf(tr * sn + ti * c) << 16);
    *reinterpret_cast<uint32_t*>(&Kb[((size_t)(b * NKV + kh) * SEQ + s) * HD + 2 * i]) = w;
  }
}

// ---------------- V transpose: qkv v-part [s][d] bf16 -> VT [d][s] bf16 ----------------
__global__ __launch_bounds__(1024) void vtrans_kernel(const u16* __restrict__ qkv,
                                                      u16* __restrict__ vt) {
  __shared__ u16 t[32][33];
  int s0 = blockIdx.x * 32, d0 = blockIdx.y * 32;
  int bk = blockIdx.z;
  int b = bk >> 2, kh = bk & 3;
  int tx = threadIdx.x, ty = threadIdx.y;
  t[ty][tx] = qkv[(size_t)(b * SEQ + s0 + ty) * NQKV + NH * HD + NKV * HD + kh * HD + d0 + tx];
  __syncthreads();
  vt[((size_t)(b * NKV + kh) * HD + d0 + ty) * SEQ + s0 + tx] = t[tx][ty];
}

// ---------------- causal flash attention, KVBLK=32, 4 blocks/CU ----------------
// grid (1024), 256 threads. Block bid: qblk = 31 - bid/32 (heavy first), bh = bid&31.
// LDS 36KB: Ks[2][32x128] (^l16 swizzle), Vs[2][64x128B] d-pair-interleaved rows
// with slot=(half*4+lg)^(row&7) swizzle, Ps[4][8x128B] q-pair-interleaved, same
// swizzle. All staging via pre-permuted global_load_lds sources (rule #21).
__global__ __launch_bounds__(256, 4) void attn_kernel(const u16* __restrict__ Q,
                                                      const u16* __restrict__ Kc,
                                                      const u16* __restrict__ VT,
                                                      u16* __restrict__ AO) {
  __shared__ u16 Ks[2][32 * 128];   // [key][d], 8KB each
  __shared__ u16 Vs[2][64 * 64];    // row = d-pair, 8KB each
  __shared__ u16 Ps[4][8 * 64];     // per-wave, row = q-pair, 1KB each
  const int bid = blockIdx.x;
  const int qblk = 31 - (bid >> 5);
  const int bh = bid & 31;
  const int b = bh >> 4, h = bh & 15;
  const int kvh = h >> 2;
  const int tid = threadIdx.x, wave = tid >> 6, lane = tid & 63;
  const int l16 = lane & 15, lg = lane >> 4;
  const int qrow0 = qblk * 64 + wave * 16;

  const u16* Kbase = Kc + (size_t)(b * NKV + kvh) * SEQ * HD;
  const u16* Vbase = VT + (size_t)(b * NKV + kvh) * HD * SEQ;

  // loop-invariant staging offsets (pre-swizzled global sources)
  int kOff[2], vOff[2], kDst[2], vDst[2];
#pragma unroll
  for (int i = 0; i < 2; ++i) {
    int chunk = i * 4 + wave;                 // 0..7
    int krow = chunk * 4 + (lane >> 4);       // 0..31
    kOff[i] = krow * HD + ((lane & 15) ^ (krow & 15)) * 8;
    kDst[i] = chunk * 512;
    int vrow = chunk * 8 + (lane >> 3);       // lds row 0..63
    int hl = (lane & 7) ^ (vrow & 7);         // (half,klg) logical slot
    int vd = vrow * 2 + (hl >> 2);            // d 0..127
    vOff[i] = vd * SEQ + (hl & 3) * 8;
    vDst[i] = chunk * 512;
  }

  bf16x8 qf[4];
  const u16* Qbase = Q + ((size_t)(b * NH + h) * SEQ + qrow0 + l16) * HD;
#pragma unroll
  for (int c = 0; c < 4; ++c) qf[c] = load_frag(Qbase + c * 32 + lg * 8);

  f32x4 o[8] = {};
  float m[4], l[4];
#pragma unroll
  for (int r = 0; r < 4; ++r) { m[r] = -3e38f; l[r] = 0.f; }

  // prologue: stage kt=0 into buf 0
#pragma unroll
  for (int i = 0; i < 2; ++i) {
    async16(&Ks[0][kDst[i]], Kbase + kOff[i]);
    async16(&Vs[0][vDst[i]], Vbase + vOff[i]);
  }

  const int nsteps = 2 * qblk + 2;
  for (int kt = 0; kt < nsteps; ++kt) {
    const int cur = kt & 1;
    const int k0 = kt * 32;
    __syncthreads(); // drains vmcnt: tile kt staged; all waves done with buf[cur]
    if (kt + 1 < nsteps) {
      const int k0n = (kt + 1) * 32;
#pragma unroll
      for (int i = 0; i < 2; ++i) {
        async16(&Ks[cur ^ 1][kDst[i]], Kbase + (size_t)k0n * HD + kOff[i]);
        async16(&Vs[cur ^ 1][vDst[i]], Vbase + k0n + vOff[i]);
      }
    }
    if (k0 > qrow0 + 15) continue; // fully masked for this wave (uniform)

    f32x4 s[2] = {};
    __builtin_amdgcn_s_setprio(1);
#pragma unroll
    for (int cb = 0; cb < 2; ++cb) {
#pragma unroll
      for (int c = 0; c < 4; ++c) {
        bf16x8 kf = load_frag(&Ks[cur][(cb * 16 + l16) * 128 + (((c * 4 + lg) ^ l16) & 15) * 8]);
        s[cb] = __builtin_amdgcn_mfma_f32_16x16x32_bf16(qf[c], kf, s[cb], 0, 0, 0);
      }
    }
    __builtin_amdgcn_s_setprio(0);

    if (k0 + 31 > qrow0) { // diagonal-crossing step: apply causal mask
#pragma unroll
      for (int cb = 0; cb < 2; ++cb) {
        int key = k0 + cb * 16 + l16;
#pragma unroll
        for (int r = 0; r < 4; ++r) {
          int rq = qrow0 + lg * 4 + r;
          if (key > rq) s[cb][r] = -1e30f;
        }
      }
    }

    // tile max per row
    float v0[4];
#pragma unroll
    for (int r = 0; r < 4; ++r) {
      float v = fmaxf(s[0][r], s[1][r]);
      v = fmaxf(v, __shfl_xor(v, 1));
      v = fmaxf(v, __shfl_xor(v, 2));
      v = fmaxf(v, __shfl_xor(v, 4));
      v = fmaxf(v, __shfl_xor(v, 8));
      v0[r] = v;
    }
    // defer-max: only rescale when some row grew by > 8 (exp2 domain)
    bool need = (v0[0] > m[0] + 8.f) || (v0[1] > m[1] + 8.f) ||
                (v0[2] > m[2] + 8.f) || (v0[3] > m[3] + 8.f);
    if (__any(need)) {
#pragma unroll
      for (int r = 0; r < 4; ++r) {
        float newm = fmaxf(m[r], v0[r]);
        float sc = exp2f(m[r] - newm);
        l[r] *= sc; m[r] = newm;
#pragma unroll
        for (int db = 0; db < 8; ++db) o[db][r] *= sc;
      }
    }
#pragma unroll
    for (int r = 0; r < 4; ++r) {
      float sum = 0.f;
      const int prow = lg * 4 + r;
      const int prr = prow >> 1;       // lds row 0..7
      const int half = r & 1;
#pragma unroll
      for (int cb = 0; cb < 2; ++cb) {
        float p = exp2f(s[cb][r] - m[r]);
        sum += p;
        int hl = half * 4 + cb * 2 + (l16 >> 3);
        int ss = hl ^ (prr & 7);
        Ps[wave][prr * 64 + ss * 8 + (l16 & 7)] = f2bf(p);
      }
      sum += __shfl_xor(sum, 1);
      sum += __shfl_xor(sum, 2);
      sum += __shfl_xor(sum, 4);
      sum += __shfl_xor(sum, 8);
      l[r] += sum;
    }

    // P A-frag: P[q=l16][key=lg*8+j]
    bf16x8 pf = load_frag(&Ps[wave][(l16 >> 1) * 64 + ((((l16 & 1) * 4 + lg) ^ ((l16 >> 1) & 7))) * 8]);
    __builtin_amdgcn_s_setprio(1);
#pragma unroll
    for (int db = 0; db < 8; ++db) {
      int vrow = db * 8 + (l16 >> 1);
      int ss = (((l16 & 1) * 4 + lg) ^ (vrow & 7));
      bf16x8 vf = load_frag(&Vs[cur][vrow * 64 + ss * 8]);
      o[db] = __builtin_amdgcn_mfma_f32_16x16x32_bf16(pf, vf, o[db], 0, 0, 0);
    }
    __builtin_amdgcn_s_setprio(0);
  }

#pragma unroll
  for (int r = 0; r < 4; ++r) {
    float inv = 1.f / l[r];
    int rq = qrow0 + lg * 4 + r;
    size_t dst = ((size_t)(b * SEQ + rq) * NH + h) * HD;
#pragma unroll
    for (int db = 0; db < 8; ++db)
      AO[dst + db * 16 + l16] = f2bf(o[db][r] * inv);
  }
}

extern "C" void kernel_launch(void* const* d_in, const int* in_sizes, int n_in,
                              void* d_out, int out_size, void* d_ws, size_t ws_size,
                              hipStream_t stream) {
  (void)in_sizes; (void)n_in; (void)out_size; (void)ws_size;
  const float* x  = (const float*)d_in[0];
  const float* fc = (const float*)d_in[1];
  const float* fs = (const float*)d_in[2];
  const float* wq = (const float*)d_in[3];
  const float* wk = (const float*)d_in[4];
  const float* wv = (const float*)d_in[5];
  const float* wo = (const float*)d_in[6];
  float* out = (float*)d_out;

  char* ws = (char*)d_ws;
  // layout (bytes):
  u16*  xb    = (u16*)(ws);                      // 4096*2048*2    = 16,777,216
  u16*  wtqkv = (u16*)(ws + 16777216);           // 3072*2048*2    = 12,582,912
  u16*  wto   = (u16*)(ws + 29360128);           // 2048*2048*2    =  8,388,608
  u16*  qkv   = (u16*)(ws + 37748736);           // 4096*3072*2    = 25,165,824 (bf16)
  u16*  Qb    = (u16*)(ws + 62914560);           // 2*16*2048*128*2= 16,777,216
  u16*  Kb    = (u16*)(ws + 79691776);           // 2*4*2048*128*2 =  4,194,304
  u16*  VTb   = (u16*)(ws + 83886080);           // 2*4*128*2048*2 =  4,194,304
  u16*  AOb   = (u16*)(ws + 37748736);           // aliases qkv (dead after pack)

  dim3 tb(32, 32);
  cast_x_kernel<<<dim3(8192), dim3(256), 0, stream>>>(x, xb);
  wtrans_kernel<<<dim3(64, 64), tb, 0, stream>>>(wq, wtqkv, 2048, 2048);
  wtrans_kernel<<<dim3(64, 16), tb, 0, stream>>>(wk, wtqkv + (size_t)2048 * 2048, 2048, 512);
  wtrans_kernel<<<dim3(64, 16), tb, 0, stream>>>(wv, wtqkv + (size_t)2560 * 2048, 2048, 512);
  wtrans_kernel<<<dim3(64, 64), tb, 0, stream>>>(wo, wto, 2048, 2048);

  gemm_bt_kernel<true><<<dim3(24, 32), dim3(256), 0, stream>>>(xb, wtqkv, qkv, MROWS, NQKV, DIMSZ);

  rope_qk_kernel<<<dim3(1024, 20), dim3(256), 0, stream>>>(qkv, fc, fs, Qb, Kb);
  vtrans_kernel<<<dim3(64, 4, 8), tb, 0, stream>>>(qkv, VTb);

  attn_kernel<<<dim3(1024), dim3(256), 0, stream>>>(Qb, Kb, VTb, AOb);

  gemm_bt_kernel<false><<<dim3(16, 32), dim3(256), 0, stream>>>(AOb, wto, out, MROWS, DIMSZ, DIMSZ);
}

// Round 6
// 234.152 us; speedup vs baseline: 1.8469x; 1.2353x over previous
//
#include <hip/hip_runtime.h>
#include <stdint.h>

#define DIMSZ 2048
#define NH 16
#define NKV 4
#define HD 128
#define BATCH 2
#define SEQ 2048
#define MROWS (BATCH*SEQ)          // 4096
#define NQKV (NH*HD + 2*NKV*HD)    // 3072

typedef unsigned short u16;
typedef float f32x4 __attribute__((ext_vector_type(4)));
typedef short short8 __attribute__((ext_vector_type(8)));
typedef __bf16 bf16x8 __attribute__((ext_vector_type(8)));
typedef unsigned short u16x4 __attribute__((ext_vector_type(4)));

__device__ __forceinline__ u16 f2bf(float f) {
  __bf16 h = (__bf16)f;           // native RNE convert
  return __builtin_bit_cast(u16, h);
}

__device__ __forceinline__ float bf2f(u16 h) {
  union { uint32_t u; float f; } v; v.u = ((uint32_t)h) << 16; return v.f;
}

__device__ __forceinline__ void async16(void* lds, const void* g) {
  __builtin_amdgcn_global_load_lds(
      (const __attribute__((address_space(1))) void*)(g),
      (__attribute__((address_space(3))) void*)(lds), 16, 0, 0);
}

__device__ __forceinline__ bf16x8 load_frag(const u16* p) {
  short8 v = *reinterpret_cast<const short8*>(p);
  return __builtin_bit_cast(bf16x8, v);
}

// ---------------- cast x fp32 -> bf16 ----------------
__global__ void cast_x_kernel(const float* __restrict__ x, u16* __restrict__ xb) {
  int i = (blockIdx.x * blockDim.x + threadIdx.x) * 4;
  float4 v = *reinterpret_cast<const float4*>(x + i);
  u16x4 o;
  o.x = f2bf(v.x); o.y = f2bf(v.y); o.z = f2bf(v.z); o.w = f2bf(v.w);
  *reinterpret_cast<u16x4*>(xb + i) = o;
}

// ------------- merged transpose-cast of all 4 weights -------------
// grid (64, 160): y<64 -> wq, y<80 -> wk, y<96 -> wv, else wo. K stride 2048.
__global__ __launch_bounds__(1024) void wtrans_all_kernel(const float* __restrict__ wq,
                                                          const float* __restrict__ wk,
                                                          const float* __restrict__ wv,
                                                          const float* __restrict__ wo,
                                                          u16* __restrict__ wtqkv,
                                                          u16* __restrict__ wto) {
  __shared__ float t[32][33];
  int y = blockIdx.y;
  const float* src; int srcN; u16* dst; int nbase;
  if (y < 64)      { src = wq; srcN = 2048; dst = wtqkv;                          nbase = y * 32; }
  else if (y < 80) { src = wk; srcN = 512;  dst = wtqkv + (size_t)2048 * 2048;    nbase = (y - 64) * 32; }
  else if (y < 96) { src = wv; srcN = 512;  dst = wtqkv + (size_t)2560 * 2048;    nbase = (y - 80) * 32; }
  else             { src = wo; srcN = 2048; dst = wto;                            nbase = (y - 96) * 32; }
  int k0 = blockIdx.x * 32;
  int tx = threadIdx.x, ty = threadIdx.y;
  t[ty][tx] = src[(size_t)(k0 + ty) * srcN + nbase + tx];
  __syncthreads();
  dst[(size_t)(nbase + ty) * 2048 + k0 + tx] = f2bf(t[tx][ty]);
}

// ---------------- GEMM: C[M][N] = A[M][K] bf16 @ BT[N][K] bf16 ----------------
// 128x128 tile, BK=64, single-buffered 32KB LDS, conflict-free XOR slot swizzle
// (phys_slot = slot ^ (row&7), staged via pre-permuted global source, rule #21).
// 1-D grid with XCD-aware swizzle (nwg must be divisible by 8).
template <bool BF16OUT>
__global__ __launch_bounds__(256) void gemm_bt_kernel(const u16* __restrict__ A,
                                                      const u16* __restrict__ BT,
                                                      void* __restrict__ Cp,
                                                      int M, int N, int K, int gx) {
  __shared__ u16 As[128 * 64];   // rows of 128B
  __shared__ u16 Bs[128 * 64];
  const int tid = threadIdx.x;
  const int wave = tid >> 6, lane = tid & 63;
  const int l16 = lane & 15, lg = lane >> 4;
  // XCD swizzle: consecutive bids round-robin XCDs; give each XCD a contiguous chunk
  const int nwg = gridDim.x;
  const int swz = (blockIdx.x & 7) * (nwg >> 3) + (blockIdx.x >> 3);
  const int bm = (swz / gx) * 128, bn = (swz % gx) * 128;
  const int wrow = (wave >> 1) * 64, wcol = (wave & 1) * 64;
  // staging map: inst i covers chunk = i*4+wave (1024B = 8 rows); per-lane
  // row = chunk*8 + lane/8, phys slot = lane&7 holds global slot (lane&7)^(row&7)
  int srow[4], scol[4];
#pragma unroll
  for (int i = 0; i < 4; ++i) {
    int chunk = i * 4 + wave;
    srow[i] = chunk * 8 + (lane >> 3);
    scol[i] = ((lane & 7) ^ (srow[i] & 7)) * 8;
  }
  f32x4 acc[4][4] = {};
  for (int k0 = 0; k0 < K; k0 += 64) {
    __syncthreads();
#pragma unroll
    for (int i = 0; i < 4; ++i) {
      async16(&As[(i * 4 + wave) * 512], &A[(size_t)(bm + srow[i]) * K + k0 + scol[i]]);
      async16(&Bs[(i * 4 + wave) * 512], &BT[(size_t)(bn + srow[i]) * K + k0 + scol[i]]);
    }
    __syncthreads();
#pragma unroll
    for (int kk = 0; kk < 2; ++kk) {
      bf16x8 af[4], bfr[4];
#pragma unroll
      for (int mb = 0; mb < 4; ++mb) {
        int row = wrow + mb * 16 + l16;
        af[mb] = load_frag(&As[row * 64 + ((kk * 4 + lg) ^ (row & 7)) * 8]);
      }
#pragma unroll
      for (int nb = 0; nb < 4; ++nb) {
        int row = wcol + nb * 16 + l16;
        bfr[nb] = load_frag(&Bs[row * 64 + ((kk * 4 + lg) ^ (row & 7)) * 8]);
      }
#pragma unroll
      for (int mb = 0; mb < 4; ++mb)
#pragma unroll
        for (int nb = 0; nb < 4; ++nb)
          acc[mb][nb] = __builtin_amdgcn_mfma_f32_16x16x32_bf16(af[mb], bfr[nb], acc[mb][nb], 0, 0, 0);
    }
  }
#pragma unroll
  for (int mb = 0; mb < 4; ++mb)
#pragma unroll
    for (int nb = 0; nb < 4; ++nb)
#pragma unroll
      for (int r = 0; r < 4; ++r) {
        size_t idx = (size_t)(bm + wrow + mb * 16 + lg * 4 + r) * N + bn + wcol + nb * 16 + l16;
        if (BF16OUT) ((u16*)Cp)[idx] = f2bf(acc[mb][nb][r]);
        else         ((float*)Cp)[idx] = acc[mb][nb][r];
      }
}

// ---------------- RoPE + pack Q and K (bf16 in / bf16 out) ----------------
// grid (1024, 20): y = head index (0..15 -> Q, 16..19 -> K)
__global__ void rope_qk_kernel(const u16* __restrict__ qkv, const float* __restrict__ fc,
                               const float* __restrict__ fs, u16* __restrict__ Qb,
                               u16* __restrict__ Kb) {
  int gi = blockIdx.x * blockDim.x + threadIdx.x; // (b*SEQ+s)*64 + i
  int i = gi & 63;
  int t = gi >> 6;          // b*SEQ + s
  int s = t & (SEQ - 1), b = t >> 11;
  int hh = blockIdx.y;
  float c = fc[s * 64 + i], sn = fs[s * 64 + i];
  if (hh < 16) {
    uint32_t pr = *reinterpret_cast<const uint32_t*>(&qkv[(size_t)t * NQKV + hh * HD + 2 * i]);
    float tr = bf2f((u16)(pr & 0xffff)), ti = bf2f((u16)(pr >> 16));
    const float qs = 0.12751689760098266f; // log2(e)/sqrt(128)
    uint32_t w = (uint32_t)f2bf((tr * c - ti * sn) * qs) |
                 ((uint32_t)f2bf((tr * sn + ti * c) * qs) << 16);
    *reinterpret_cast<uint32_t*>(&Qb[((size_t)(b * NH + hh) * SEQ + s) * HD + 2 * i]) = w;
  } else {
    int kh = hh - 16;
    uint32_t pr = *reinterpret_cast<const uint32_t*>(&qkv[(size_t)t * NQKV + NH * HD + kh * HD + 2 * i]);
    float tr = bf2f((u16)(pr & 0xffff)), ti = bf2f((u16)(pr >> 16));
    uint32_t w = (uint32_t)f2bf(tr * c - ti * sn) |
                 ((uint32_t)f2bf(tr * sn + ti * c) << 16);
    *reinterpret_cast<uint32_t*>(&Kb[((size_t)(b * NKV + kh) * SEQ + s) * HD + 2 * i]) = w;
  }
}

// ---------------- V transpose: qkv v-part [s][d] bf16 -> VT [d][s] bf16 ----------------
__global__ __launch_bounds__(1024) void vtrans_kernel(const u16* __restrict__ qkv,
                                                      u16* __restrict__ vt) {
  __shared__ u16 t[32][33];
  int s0 = blockIdx.x * 32, d0 = blockIdx.y * 32;
  int bk = blockIdx.z;
  int b = bk >> 2, kh = bk & 3;
  int tx = threadIdx.x, ty = threadIdx.y;
  t[ty][tx] = qkv[(size_t)(b * SEQ + s0 + ty) * NQKV + NH * HD + NKV * HD + kh * HD + d0 + tx];
  __syncthreads();
  vt[((size_t)(b * NKV + kh) * HD + d0 + ty) * SEQ + s0 + tx] = t[tx][ty];
}

// ---------------- causal flash attention (round-3 structure + MFMA row-sum) ----
// grid (16, NH, BATCH), 256 threads. Block p handles q-tiles {31-p, p}.
// Double-buffered K/V LDS, one barrier per KV-step, defer-max softmax (exp2
// domain, log2e folded into Q), setprio around MFMA clusters. Row-sum of P is
// accumulated via MFMA against an all-ones B fragment (no sum shuffles).
__global__ __launch_bounds__(256) void attn_kernel(const u16* __restrict__ Q,
                                                   const u16* __restrict__ Kc,
                                                   const u16* __restrict__ VT,
                                                   u16* __restrict__ AO) {
  __shared__ u16 Ks[2][64 * 128];   // [key][d], swizzled
  __shared__ u16 Vs[2][128 * 64];   // [d][key], swizzled
  __shared__ u16 Ps[4][16 * 64];    // per-wave P tile [qrow][key], swizzled
  const int pairi = blockIdx.x;     // 0..15
  const int h = blockIdx.y, b = blockIdx.z;
  const int kvh = h >> 2;
  const int tid = threadIdx.x, wave = tid >> 6, lane = tid & 63;
  const int l16 = lane & 15, lg = lane >> 4;

  const u16* Kbase = Kc + (size_t)(b * NKV + kvh) * SEQ * HD;
  const u16* Vbase = VT + (size_t)(b * NKV + kvh) * HD * SEQ;

  // all-ones bf16 B-fragment for row-sum MFMA
  bf16x8 onesf;
#pragma unroll
  for (int j = 0; j < 8; ++j) onesf[j] = __builtin_bit_cast(__bf16, (u16)0x3F80);

  // per-thread staging offsets (loop-invariant)
  int kOff[4], vOff[4], kDst[4], vDst[4];
#pragma unroll
  for (int i = 0; i < 4; ++i) {
    int chunk = i * 4 + wave;                 // 0..15
    int krow = chunk * 4 + (lane >> 4);       // 0..63
    kOff[i] = krow * HD + ((lane & 15) ^ (krow & 15)) * 8;
    kDst[i] = chunk * 512;
    int vrow = chunk * 8 + (lane >> 3);       // 0..127
    vOff[i] = vrow * SEQ + ((lane & 7) ^ (vrow & 7)) * 8;
    vDst[i] = chunk * 512;
  }

  for (int sel = 0; sel < 2; ++sel) {
    const int qblk = sel ? pairi : (31 - pairi);
    const int qrow0 = qblk * 64 + wave * 16;

    bf16x8 qf[4];
    const u16* Qbase = Q + ((size_t)(b * NH + h) * SEQ + qrow0 + l16) * HD;
#pragma unroll
    for (int c = 0; c < 4; ++c) qf[c] = load_frag(Qbase + c * 32 + lg * 8);

    f32x4 o[8] = {};
    f32x4 lsum = {};
    float m[4];
#pragma unroll
    for (int r = 0; r < 4; ++r) m[r] = -3e38f;

    __syncthreads(); // all waves done with LDS from previous q-tile
    // prologue: stage kt=0 into buf 0
#pragma unroll
    for (int i = 0; i < 4; ++i) {
      async16(&Ks[0][kDst[i]], Kbase + kOff[i]);
      async16(&Vs[0][vDst[i]], Vbase + vOff[i]);
    }

    for (int kt = 0; kt <= qblk; ++kt) {
      const int cur = kt & 1;
      __syncthreads(); // drains vmcnt: tile kt staged; all waves done with buf[cur]
      if (kt < qblk) {
        const int k0n = (kt + 1) * 64;
#pragma unroll
        for (int i = 0; i < 4; ++i) {
          async16(&Ks[cur ^ 1][kDst[i]], Kbase + (size_t)k0n * HD + kOff[i]);
          async16(&Vs[cur ^ 1][vDst[i]], Vbase + k0n + vOff[i]);
        }
      }

      f32x4 s[4] = {};
      __builtin_amdgcn_s_setprio(1);
#pragma unroll
      for (int cb = 0; cb < 4; ++cb) {
#pragma unroll
        for (int c = 0; c < 4; ++c) {
          bf16x8 kf = load_frag(&Ks[cur][(cb * 16 + l16) * 128 + (((c * 4 + lg) ^ l16) & 15) * 8]);
          s[cb] = __builtin_amdgcn_mfma_f32_16x16x32_bf16(qf[c], kf, s[cb], 0, 0, 0);
        }
      }
      __builtin_amdgcn_s_setprio(0);

      if (kt == qblk) { // only the diagonal tile needs masking
        const int k0 = kt * 64;
#pragma unroll
        for (int cb = 0; cb < 4; ++cb) {
          int key = k0 + cb * 16 + l16;
#pragma unroll
          for (int r = 0; r < 4; ++r) {
            int rq = qrow0 + lg * 4 + r;
            if (key > rq) s[cb][r] = -1e30f;
          }
        }
      }

      // tile max per row
      float v0[4];
#pragma unroll
      for (int r = 0; r < 4; ++r) {
        float v = fmaxf(fmaxf(s[0][r], s[1][r]), fmaxf(s[2][r], s[3][r]));
        v = fmaxf(v, __shfl_xor(v, 1));
        v = fmaxf(v, __shfl_xor(v, 2));
        v = fmaxf(v, __shfl_xor(v, 4));
        v = fmaxf(v, __shfl_xor(v, 8));
        v0[r] = v;
      }
      // defer-max: only rescale when some row grew by > 8 (exp2 domain)
      bool need = (v0[0] > m[0] + 8.f) || (v0[1] > m[1] + 8.f) ||
                  (v0[2] > m[2] + 8.f) || (v0[3] > m[3] + 8.f);
      if (__any(need)) {
#pragma unroll
        for (int r = 0; r < 4; ++r) {
          float newm = fmaxf(m[r], v0[r]);
          float sc = exp2f(m[r] - newm);
          lsum[r] *= sc; m[r] = newm;
#pragma unroll
          for (int db = 0; db < 8; ++db) o[db][r] *= sc;
        }
      }
#pragma unroll
      for (int r = 0; r < 4; ++r) {
        int prow = lg * 4 + r;
#pragma unroll
        for (int cb = 0; cb < 4; ++cb) {
          float p = exp2f(s[cb][r] - m[r]);
          Ps[wave][(prow * 64 + cb * 16 + l16) ^ ((prow & 7) << 3)] = f2bf(p);
        }
      }

      bf16x8 pf[2];
#pragma unroll
      for (int c = 0; c < 2; ++c)
        pf[c] = load_frag(&Ps[wave][(l16 * 64 + c * 32 + lg * 8) ^ ((l16 & 7) << 3)]);
      __builtin_amdgcn_s_setprio(1);
#pragma unroll
      for (int c = 0; c < 2; ++c)
        lsum = __builtin_amdgcn_mfma_f32_16x16x32_bf16(pf[c], onesf, lsum, 0, 0, 0);
#pragma unroll
      for (int db = 0; db < 8; ++db) {
#pragma unroll
        for (int c = 0; c < 2; ++c) {
          bf16x8 vf = load_frag(&Vs[cur][(db * 16 + l16) * 64 + ((c * 4 + lg) ^ (l16 & 7)) * 8]);
          o[db] = __builtin_amdgcn_mfma_f32_16x16x32_bf16(pf[c], vf, o[db], 0, 0, 0);
        }
      }
      __builtin_amdgcn_s_setprio(0);
    }

#pragma unroll
    for (int r = 0; r < 4; ++r) {
      float inv = 1.f / lsum[r];
      int rq = qrow0 + lg * 4 + r;
      size_t dst = ((size_t)(b * SEQ + rq) * NH + h) * HD;
#pragma unroll
      for (int db = 0; db < 8; ++db)
        AO[dst + db * 16 + l16] = f2bf(o[db][r] * inv);
    }
  }
}

extern "C" void kernel_launch(void* const* d_in, const int* in_sizes, int n_in,
                              void* d_out, int out_size, void* d_ws, size_t ws_size,
                              hipStream_t stream) {
  (void)in_sizes; (void)n_in; (void)out_size; (void)ws_size;
  const float* x  = (const float*)d_in[0];
  const float* fc = (const float*)d_in[1];
  const float* fs = (const float*)d_in[2];
  const float* wq = (const float*)d_in[3];
  const float* wk = (const float*)d_in[4];
  const float* wv = (const float*)d_in[5];
  const float* wo = (const float*)d_in[6];
  float* out = (float*)d_out;

  char* ws = (char*)d_ws;
  // layout (bytes):
  u16*  xb    = (u16*)(ws);                      // 4096*2048*2    = 16,777,216
  u16*  wtqkv = (u16*)(ws + 16777216);           // 3072*2048*2    = 12,582,912
  u16*  wto   = (u16*)(ws + 29360128);           // 2048*2048*2    =  8,388,608
  u16*  qkv   = (u16*)(ws + 37748736);           // 4096*3072*2    = 25,165,824 (bf16)
  u16*  Qb    = (u16*)(ws + 62914560);           // 2*16*2048*128*2= 16,777,216
  u16*  Kb    = (u16*)(ws + 79691776);           // 2*4*2048*128*2 =  4,194,304
  u16*  VTb   = (u16*)(ws + 83886080);           // 2*4*128*2048*2 =  4,194,304
  u16*  AOb   = (u16*)(ws + 37748736);           // aliases qkv (dead after pack)

  cast_x_kernel<<<dim3(8192), dim3(256), 0, stream>>>(x, xb);
  wtrans_all_kernel<<<dim3(64, 160), dim3(32, 32), 0, stream>>>(wq, wk, wv, wo, wtqkv, wto);

  gemm_bt_kernel<true><<<dim3(768), dim3(256), 0, stream>>>(xb, wtqkv, qkv, MROWS, NQKV, DIMSZ, 24);

  rope_qk_kernel<<<dim3(1024, 20), dim3(256), 0, stream>>>(qkv, fc, fs, Qb, Kb);
  vtrans_kernel<<<dim3(64, 4, 8), dim3(32, 32), 0, stream>>>(qkv, VTb);

  attn_kernel<<<dim3(16, 16, 2), dim3(256), 0, stream>>>(Qb, Kb, VTb, AOb);

  gemm_bt_kernel<false><<<dim3(512), dim3(256), 0, stream>>>(AOb, wto, out, MROWS, DIMSZ, DIMSZ, 16);
}